// Round 3
// baseline (4100.901 us; speedup 1.0000x reference)
//
#include <hip/hip_runtime.h>
#include <stdint.h>
#include <math.h>

// Persistent bidirectional-LSTM encoder for MI355X (gfx950).
// B=64, T=512, D_IN=512, H=1024. ALL I/O IS FLOAT32 (per the reference);
// MFMA compute in bf16 (round-nearest inputs), f32 accumulate, f32 output.
//
// Partition: 256 WGs x 512 threads. wg = [group(2) | dir(2) | seg(64)]
//   group: batch rows 32g..32g+31; dir: fwd/bwd scan; seg: 16 hidden units.
// K split UNIFORM across 8 waves: each wave owns 64 x-cols + 128 h-cols.
//
// Sync design v3 — DATA-AS-FLAG (no flag array at all):
//  - h ring buffer is 4 parities deep: h(t) lives at parity t&3.
//  - at step t each producer pre-poisons its own region of parity (t+1)&3
//    with sentinel 0xFFFF (bf16 NaN; |h|<1 so unreachable). The mid-step
//    __syncthreads drains the poison to L3 (vmcnt0) BEFORE h(t) publishes,
//    so any consumer that has seen h(t) can never read stale pre-poison
//    data in parity t+1 — this replaces the flag's ordering role.
//  - consumers poll their OWN h fragments until sentinel-free: the
//    successful poll pass IS the data (1 L3 round trip, no fence, no flag
//    line contention). Each wave self-releases on just its 8 producers.
//  - skew <= 1 step (a WG passes step t only after all its producers
//    published h(t-1)), which makes the mod-4 parity rotation race-free:
//    parity (t+1)&3 has no readers (they'd be at step t-2) and no foreign
//    writers (they'd be at t+1, writing their own disjoint region).
//  - end-of-loop barrier is raw s_barrier + lgkmcnt(0) only (protects LDS
//    part[] reuse); h/out store acks are NOT waited on by the producer —
//    they drain a full phase later at the next mid-sync.

#define TSEQ 512
#define DIN  512

typedef short  short8  __attribute__((ext_vector_type(8)));
typedef float  float4_ __attribute__((ext_vector_type(4)));
typedef float  float8_ __attribute__((ext_vector_type(8)));

__device__ __forceinline__ unsigned short f2bf(float f) {
  union { float f; unsigned int i; } v; v.f = f;
  unsigned int r = (v.i + 0x7FFFu + ((v.i >> 16) & 1u)) >> 16;
  return (unsigned short)r;
}
// 8 consecutive f32 -> bf16x8 fragment (round-nearest-even)
__device__ __forceinline__ short8 cvt8(const float* p) {
  float8_ f = *reinterpret_cast<const float8_*>(p);
  short8 s;
  #pragma unroll
  for (int i = 0; i < 8; ++i) s[i] = (short)f2bf(f[i]);
  return s;
}
// 16B (8 bf16) read through the coherence point: 2 x 8B relaxed agent atomics.
__device__ __forceinline__ short8 ald16(const unsigned long long* b64, size_t elem) {
  union { unsigned long long u[2]; short8 s; } v;
  const unsigned long long* p = b64 + (elem >> 2);
  v.u[0] = __hip_atomic_load(p,     __ATOMIC_RELAXED, __HIP_MEMORY_SCOPE_AGENT);
  v.u[1] = __hip_atomic_load(p + 1, __ATOMIC_RELAXED, __HIP_MEMORY_SCOPE_AGENT);
  return v.s;
}
__device__ __forceinline__ float sigf(float x) {
  x = fminf(fmaxf(x, -30.f), 30.f);
  return 1.f / (1.f + expf(-x));
}

__global__ __launch_bounds__(512, 2)
void lstm_encoder_kernel(
    const float* __restrict__ x,
    const float* __restrict__ Wih_f, const float* __restrict__ Whh_f,
    const float* __restrict__ bih_f, const float* __restrict__ bhh_f,
    const float* __restrict__ Wih_b, const float* __restrict__ Whh_b,
    const float* __restrict__ bih_b, const float* __restrict__ bhh_b,
    const float* __restrict__ fcW, const float* __restrict__ fcb,
    const float* __restrict__ fhW, const float* __restrict__ fhb,
    float* __restrict__ out,
    int* __restrict__ done,
    unsigned short* __restrict__ hbuf_f, unsigned short* __restrict__ hbuf_b,
    unsigned short* __restrict__ cend)
{
  __shared__ float part[8][4][32][18];   // [wave][gate][Mrow][unit(+pad)]

  const int tid  = threadIdx.x;
  const int wv   = tid >> 6;
  const int lane = tid & 63;
  const int quad = lane >> 4;
  const int u16  = lane & 15;

  const int wg    = blockIdx.x;
  const int group = wg >> 7;
  const int rem   = wg & 127;
  const int dir   = rem >> 6;
  const int seg   = rem & 63;
  const int j0    = seg * 16;

  const float* Wih = dir ? Wih_b : Wih_f;
  const float* Whh = dir ? Whh_b : Whh_f;
  const float* bih = dir ? bih_b : bih_f;
  const float* bhh = dir ? bhh_b : bhh_f;
  unsigned short* hbuf = dir ? hbuf_b : hbuf_f;
  const unsigned long long* hbuf64 = (const unsigned long long*)hbuf;
  unsigned int* hbuf32 = (unsigned int*)hbuf;

  // uniform K split: wave wv owns x-cols [wv*64, wv*64+64) (chunks 0-1)
  // and h-cols [wv*128, wv*128+128) (chunks 2-5)
  const int wx = wv * 64;
  const int wh = wv * 128;

  // stationary bf16 weight fragments: B[k][n=lane&15], 8 contiguous k/lane
  short8 Bf[6][4];
  #pragma unroll
  for (int kc = 0; kc < 6; ++kc) {
    #pragma unroll
    for (int nt = 0; nt < 4; ++nt) {
      const int row = nt * 1024 + j0 + u16;          // gate nt, unit j0+u16
      const float* p = (kc < 2)
          ? (Wih + (size_t)row * 512  + (wx + kc * 32 + quad * 8))
          : (Whh + (size_t)row * 1024 + (wh + (kc - 2) * 32 + quad * 8));
      Bf[kc][nt] = cvt8(p);
    }
  }
  float bias[4];
  #pragma unroll
  for (int g = 0; g < 4; ++g)
    bias[g] = bih[g * 1024 + j0 + u16] + bhh[g * 1024 + j0 + u16];

  float4_ acc[2][4];
  #pragma unroll
  for (int mt = 0; mt < 2; ++mt)
    #pragma unroll
    for (int nt = 0; nt < 4; ++nt) acc[mt][nt] = (float4_){0.f, 0.f, 0.f, 0.f};

  float cstate = 0.f;
  const int arow0 = group * 32 + u16;

  auto gemm_x = [&](int t) {
    const int tx = dir ? (TSEQ - 1 - t) : t;
    #pragma unroll
    for (int kc = 0; kc < 2; ++kc) {
      const int klane = wx + kc * 32 + quad * 8;
      const float* base = x + ((size_t)arow0 * TSEQ + tx) * DIN + klane;
      short8 a0 = cvt8(base);
      short8 a1 = cvt8(base + (size_t)16 * TSEQ * DIN);
      #pragma unroll
      for (int nt = 0; nt < 4; ++nt) {
        acc[0][nt] = __builtin_amdgcn_mfma_f32_16x16x32_bf16(a0, Bf[kc][nt], acc[0][nt], 0, 0, 0);
        acc[1][nt] = __builtin_amdgcn_mfma_f32_16x16x32_bf16(a1, Bf[kc][nt], acc[1][nt], 0, 0, 0);
      }
    }
  };

  // recurrent part with DATA-POLL: load own fragments of parity (t-1)&3
  // until sentinel-free, then MFMA straight out of the polled registers.
  auto gemm_h = [&](int t) {
    const int rp = (t + 3) & 3;               // parity holding h(t-1)
    const unsigned long long* base[4];
    #pragma unroll
    for (int kc = 0; kc < 4; ++kc) {
      const int kh = wh + kc * 32 + quad * 8;
      base[kc] = hbuf64 + ((((size_t)(rp * 64 + arow0)) * 1024 + kh) >> 2);
    }
    unsigned long long v[4][4];
    int it = 0;
    for (;;) {
      #pragma unroll
      for (int kc = 0; kc < 4; ++kc) {
        v[kc][0] = __hip_atomic_load(base[kc],        __ATOMIC_RELAXED, __HIP_MEMORY_SCOPE_AGENT);
        v[kc][1] = __hip_atomic_load(base[kc] + 1,    __ATOMIC_RELAXED, __HIP_MEMORY_SCOPE_AGENT);
        v[kc][2] = __hip_atomic_load(base[kc] + 4096, __ATOMIC_RELAXED, __HIP_MEMORY_SCOPE_AGENT);
        v[kc][3] = __hip_atomic_load(base[kc] + 4097, __ATOMIC_RELAXED, __HIP_MEMORY_SCOPE_AGENT);
      }
      // sentinel scan: any 16-bit lane == 0xFFFF  <=>  ~v has a zero lane
      unsigned long long bad = 0;
      #pragma unroll
      for (int kc = 0; kc < 4; ++kc)
        #pragma unroll
        for (int j = 0; j < 4; ++j) {
          unsigned long long y = ~v[kc][j];
          bad |= (y - 0x0001000100010001ull) & ~y & 0x8000800080008000ull;
        }
      if (__ballot(bad != 0) == 0ull) break;
      if (++it > 200000) break;               // bounded: never hard-hang
      if (it < 4) __builtin_amdgcn_s_sleep(1);
      else        __builtin_amdgcn_s_sleep(4);
    }
    #pragma unroll
    for (int kc = 0; kc < 4; ++kc) {
      union { unsigned long long u[2]; short8 s; } a0, a1;
      a0.u[0] = v[kc][0]; a0.u[1] = v[kc][1];
      a1.u[0] = v[kc][2]; a1.u[1] = v[kc][3];
      #pragma unroll
      for (int nt = 0; nt < 4; ++nt) {
        acc[0][nt] = __builtin_amdgcn_mfma_f32_16x16x32_bf16(a0.s, Bf[kc + 2][nt], acc[0][nt], 0, 0, 0);
        acc[1][nt] = __builtin_amdgcn_mfma_f32_16x16x32_bf16(a1.s, Bf[kc + 2][nt], acc[1][nt], 0, 0, 0);
      }
    }
  };

  gemm_x(0);                                  // x-part of step 0 (all waves)

  const int row_l = wv * 4 + quad;
  const int bglob = group * 32 + row_l;

  for (int t = 0; t < TSEQ; ++t) {
    // pre-poison parity (t+1)&3 of MY seg region with sentinel.
    // Safe: its readers would be at step t-2 (all peers are >= t-1), its
    // only writer at t+1 writes a disjoint region. Drained to L3 by the
    // mid-step __syncthreads BELOW, i.e. before h(t) publishes.
    {
      const int rq = (t + 1) & 3;
      if (tid < 256) {
        const int rr = group * 32 + (tid >> 3);
        const int uu = j0 + ((tid & 7) << 1);
        const size_t elem = (size_t)(rq * 64 + rr) * 1024 + uu;
        __hip_atomic_store(hbuf32 + (elem >> 1), 0xFFFFFFFFu,
                           __ATOMIC_RELAXED, __HIP_MEMORY_SCOPE_AGENT);
      }
    }

    gemm_h(t);                                // per-wave data-poll + MFMA

    #pragma unroll
    for (int mt = 0; mt < 2; ++mt)
      #pragma unroll
      for (int nt = 0; nt < 4; ++nt)
        #pragma unroll
        for (int r = 0; r < 4; ++r)
          part[wv][nt][mt * 16 + quad * 4 + r][u16] = acc[mt][nt][r];
    __syncthreads();   // FULL sync: drains poison stores to L3 (vmcnt 0)

    float gts[4];
    #pragma unroll
    for (int g = 0; g < 4; ++g) {
      float s = bias[g];
      #pragma unroll
      for (int p = 0; p < 8; ++p) s += part[p][g][row_l][u16];
      gts[g] = s;
    }
    float iv = sigf(gts[0]);
    float fv = sigf(gts[1]);
    float gv = tanhf(gts[2]);
    float ov = sigf(gts[3]);
    cstate = fv * cstate + iv * gv;
    float hv = ov * tanhf(cstate);
    unsigned short h16 = f2bf(hv);

    // publish h(t) at parity t&3: packed bf16 pairs, relaxed agent stores.
    // No ack wait — consumers detect the data itself.
    {
      unsigned int h32 = h16;
      unsigned int oth = __shfl_xor(h32, 1);
      if ((u16 & 1) == 0) {
        unsigned int val = h32 | (oth << 16);
        size_t elem = (size_t)((t & 3) * 64 + bglob) * 1024 + j0 + u16;
        __hip_atomic_store(hbuf32 + (elem >> 1), val,
                           __ATOMIC_RELAXED, __HIP_MEMORY_SCOPE_AGENT);
      }
    }

    // end barrier: LDS-only (protects part[] reuse). h/out stores stay in
    // flight; they drain at the NEXT mid-step __syncthreads.
    asm volatile("s_waitcnt lgkmcnt(0)" ::: "memory");
    __builtin_amdgcn_s_barrier();
    __builtin_amdgcn_sched_barrier(0);

    // hidden_states[b][t][dir*1024+j] in FULL f32 — off the critical path
    out[((size_t)bglob * TSEQ + t) * 2048 + dir * 1024 + j0 + u16] = hv;

    #pragma unroll
    for (int mt = 0; mt < 2; ++mt)
      #pragma unroll
      for (int nt = 0; nt < 4; ++nt) acc[mt][nt] = (float4_){0.f, 0.f, 0.f, 0.f};
    if (t + 1 < TSEQ) gemm_x(t + 1);          // x-part of t+1 in poll shadow
  }

  // publish final cell state (bf16, coherence-point)
  {
    unsigned short c16 = f2bf(cstate);
    unsigned int c32 = c16;
    unsigned int oth = __shfl_xor(c32, 1);
    if ((u16 & 1) == 0) {
      size_t elem = (size_t)bglob * 2048 + dir * 1024 + j0 + u16;
      __hip_atomic_store((unsigned int*)cend + (elem >> 1), c32 | (oth << 16),
                         __ATOMIC_RELAXED, __HIP_MEMORY_SCOPE_AGENT);
    }
  }
  __syncthreads();                            // FULL: drain cend + out stores
  if (tid == 0)
    __hip_atomic_store(done + wg, 1, __ATOMIC_RELAXED, __HIP_MEMORY_SCOPE_AGENT);
  if (wg >= 128) return;                      // only epilogue WGs wait

  {
    int it = 0;
    for (;;) {
      int ok = 1;
      #pragma unroll
      for (int j = 0; j < 4; ++j) {
        int v = __hip_atomic_load(done + lane * 4 + j, __ATOMIC_RELAXED, __HIP_MEMORY_SCOPE_AGENT);
        ok &= (v != 0);
      }
      if (__ballot(!ok) == 0ull) break;
      if (++it > 300000) break;
      __builtin_amdgcn_s_sleep(4);
    }
    __builtin_amdgcn_fence(__ATOMIC_ACQUIRE, "workgroup");
    __builtin_amdgcn_sched_barrier(0);
  }
  if (wv >= 4) return;

  // epilogue: initial_hiddens = tanh(h_end @ fh_W^T + fh_b)   (mat 0)
  //           initial_cells   = tanh(c_end @ fc_W^T + fc_b)   (mat 1)
  const int mat   = wg >> 6;
  const int nbase = (wg & 63) * 16;
  const float* Wp = mat ? fcW : fhW;
  const float* bp = mat ? fcb : fhb;
  const int m0 = wv * 16;
  const int am = m0 + u16;
  const unsigned long long* hf64 = (const unsigned long long*)hbuf_f;
  const unsigned long long* hb64 = (const unsigned long long*)hbuf_b;
  const unsigned long long* ce64 = (const unsigned long long*)cend;
  float4_ a4 = (float4_){0.f, 0.f, 0.f, 0.f};
  #pragma unroll 4
  for (int kc = 0; kc < 64; ++kc) {
    const int k = kc * 32 + quad * 8;
    short8 av, bv;
    if (mat == 0) {                          // h(511) lives at parity 3
      av = (kc < 32) ? ald16(hf64, (size_t)(192 + am) * 1024 + k)
                     : ald16(hb64, (size_t)(192 + am) * 1024 + (k - 1024));
    } else {
      av = ald16(ce64, (size_t)am * 2048 + k);
    }
    bv = cvt8(Wp + (size_t)(nbase + u16) * 2048 + k);
    a4 = __builtin_amdgcn_mfma_f32_16x16x32_bf16(av, bv, a4, 0, 0, 0);
  }
  float bb = bp[nbase + u16];
  #pragma unroll
  for (int r = 0; r < 4; ++r) {
    const int row = m0 + quad * 4 + r;
    float v = tanhf(a4[r] + bb);
    out[(size_t)67108864 + (size_t)mat * 65536 + (size_t)row * 1024 + nbase + u16] = v;
  }
}

extern "C" void kernel_launch(void* const* d_in, const int* in_sizes, int n_in,
                              void* d_out, int out_size, void* d_ws, size_t ws_size,
                              hipStream_t stream) {
  char* ws = (char*)d_ws;
  // ws map: [0,1KB) done (256 ints, 4KB reserved),
  //         [4KB, +512KB) h_f 4-parity ring, +512KB h_b ring, +256KB c_end
  int* done = (int*)(ws);
  unsigned short* hf = (unsigned short*)(ws + 4096);
  unsigned short* hb = (unsigned short*)(ws + 4096 + 524288);
  unsigned short* ce = (unsigned short*)(ws + 4096 + 1048576);
  (void)hipMemsetAsync(ws, 0, 4096, stream);                   // done = 0
  (void)hipMemsetAsync(hf, 0xFF, 393216, stream);              // parities 0-2 poison
  (void)hipMemsetAsync((char*)hf + 393216, 0, 131072, stream); // parity 3 = h(-1) = 0
  (void)hipMemsetAsync(hb, 0xFF, 393216, stream);
  (void)hipMemsetAsync((char*)hb + 393216, 0, 131072, stream);
  lstm_encoder_kernel<<<256, 512, 0, stream>>>(
      (const float*)d_in[0],
      (const float*)d_in[1], (const float*)d_in[2],
      (const float*)d_in[3], (const float*)d_in[4],
      (const float*)d_in[5], (const float*)d_in[6],
      (const float*)d_in[7], (const float*)d_in[8],
      (const float*)d_in[9], (const float*)d_in[10],
      (const float*)d_in[11], (const float*)d_in[12],
      (float*)d_out, done, hf, hb, ce);
}

// Round 4
// 3845.110 us; speedup vs baseline: 1.0665x; 1.0665x over previous
//
#include <hip/hip_runtime.h>
#include <stdint.h>
#include <math.h>

// Persistent bidirectional-LSTM encoder for MI355X (gfx950).
// B=64, T=512, D_IN=512, H=1024. ALL I/O IS FLOAT32 (per the reference);
// MFMA compute in bf16 (round-nearest inputs), f32 accumulate, f32 output.
//
// Partition: 256 WGs x 512 threads. wg = [group(2) | dir(2) | seg(64)]
// K split UNIFORM across 8 waves: each wave owns 64 x-cols + 128 h-cols.
//
// Sync design v3 (data-as-flag, 4-parity poisoned ring) — see r1/r3 notes.
// v4 deltas (sync structure FROZEN, step internals only):
//  - x(t+1) loads issued into REGISTERS right after SYNC1; converted and
//    MFMA'd at the tail ~microseconds later -> HBM-miss latency (x gets
//    evicted from L3 by the out[] stream; FETCH_SIZE proves HBM re-reads)
//    no longer stalls the serial loop.
//  - launch_bounds(512,1): we run 1 WG/CU anyway; frees VGPR headroom
//    for the 32-reg x staging buffer (was capped at 128).
//  - activations via __expf/__fdividef (v_exp_f32) instead of libm
//    expf/tanhf: ~4-6 instr per gate instead of ~20+, off the
//    detect->publish critical path.

#define TSEQ 512
#define DIN  512

typedef short  short8  __attribute__((ext_vector_type(8)));
typedef float  float4_ __attribute__((ext_vector_type(4)));
typedef float  float8_ __attribute__((ext_vector_type(8)));

__device__ __forceinline__ unsigned short f2bf(float f) {
  union { float f; unsigned int i; } v; v.f = f;
  unsigned int r = (v.i + 0x7FFFu + ((v.i >> 16) & 1u)) >> 16;
  return (unsigned short)r;
}
// 8 consecutive f32 -> bf16x8 fragment (round-nearest-even)
__device__ __forceinline__ short8 cvt8(const float* p) {
  float8_ f = *reinterpret_cast<const float8_*>(p);
  short8 s;
  #pragma unroll
  for (int i = 0; i < 8; ++i) s[i] = (short)f2bf(f[i]);
  return s;
}
// convert an already-loaded float8 register to bf16x8
__device__ __forceinline__ short8 cvt8v(float8_ f) {
  short8 s;
  #pragma unroll
  for (int i = 0; i < 8; ++i) s[i] = (short)f2bf(f[i]);
  return s;
}
// 16B (8 bf16) read through the coherence point: 2 x 8B relaxed agent atomics.
__device__ __forceinline__ short8 ald16(const unsigned long long* b64, size_t elem) {
  union { unsigned long long u[2]; short8 s; } v;
  const unsigned long long* p = b64 + (elem >> 2);
  v.u[0] = __hip_atomic_load(p,     __ATOMIC_RELAXED, __HIP_MEMORY_SCOPE_AGENT);
  v.u[1] = __hip_atomic_load(p + 1, __ATOMIC_RELAXED, __HIP_MEMORY_SCOPE_AGENT);
  return v.s;
}
// fast activations: v_exp_f32-based. |err| ~1e-6 rel — far below the
// bf16 h-quantization already in the pipeline.
__device__ __forceinline__ float fsig(float x) {
  x = fminf(fmaxf(x, -30.f), 30.f);
  return __fdividef(1.f, 1.f + __expf(-x));
}
__device__ __forceinline__ float ftanh(float x) {
  x = fminf(fmaxf(x, -15.f), 15.f);
  return 1.f - __fdividef(2.f, __expf(2.f * x) + 1.f);
}

__global__ __launch_bounds__(512, 1)
void lstm_encoder_kernel(
    const float* __restrict__ x,
    const float* __restrict__ Wih_f, const float* __restrict__ Whh_f,
    const float* __restrict__ bih_f, const float* __restrict__ bhh_f,
    const float* __restrict__ Wih_b, const float* __restrict__ Whh_b,
    const float* __restrict__ bih_b, const float* __restrict__ bhh_b,
    const float* __restrict__ fcW, const float* __restrict__ fcb,
    const float* __restrict__ fhW, const float* __restrict__ fhb,
    float* __restrict__ out,
    int* __restrict__ done,
    unsigned short* __restrict__ hbuf_f, unsigned short* __restrict__ hbuf_b,
    unsigned short* __restrict__ cend)
{
  __shared__ float part[8][4][32][18];   // [wave][gate][Mrow][unit(+pad)]

  const int tid  = threadIdx.x;
  const int wv   = tid >> 6;
  const int lane = tid & 63;
  const int quad = lane >> 4;
  const int u16  = lane & 15;

  const int wg    = blockIdx.x;
  const int group = wg >> 7;
  const int rem   = wg & 127;
  const int dir   = rem >> 6;
  const int seg   = rem & 63;
  const int j0    = seg * 16;

  const float* Wih = dir ? Wih_b : Wih_f;
  const float* Whh = dir ? Whh_b : Whh_f;
  const float* bih = dir ? bih_b : bih_f;
  const float* bhh = dir ? bhh_b : bhh_f;
  unsigned short* hbuf = dir ? hbuf_b : hbuf_f;
  const unsigned long long* hbuf64 = (const unsigned long long*)hbuf;
  unsigned int* hbuf32 = (unsigned int*)hbuf;

  const int wx = wv * 64;
  const int wh = wv * 128;

  // stationary bf16 weight fragments: B[k][n=lane&15], 8 contiguous k/lane
  short8 Bf[6][4];
  #pragma unroll
  for (int kc = 0; kc < 6; ++kc) {
    #pragma unroll
    for (int nt = 0; nt < 4; ++nt) {
      const int row = nt * 1024 + j0 + u16;          // gate nt, unit j0+u16
      const float* p = (kc < 2)
          ? (Wih + (size_t)row * 512  + (wx + kc * 32 + quad * 8))
          : (Whh + (size_t)row * 1024 + (wh + (kc - 2) * 32 + quad * 8));
      Bf[kc][nt] = cvt8(p);
    }
  }
  float bias[4];
  #pragma unroll
  for (int g = 0; g < 4; ++g)
    bias[g] = bih[g * 1024 + j0 + u16] + bhh[g * 1024 + j0 + u16];

  float4_ acc[2][4];
  #pragma unroll
  for (int mt = 0; mt < 2; ++mt)
    #pragma unroll
    for (int nt = 0; nt < 4; ++nt) acc[mt][nt] = (float4_){0.f, 0.f, 0.f, 0.f};

  float cstate = 0.f;
  const int arow0 = group * 32 + u16;

  // x staging registers (raw f32; converted at consume time)
  float8_ xr[2][2];                       // [kc][mt]
  auto xload = [&](int t) {
    const int tx = dir ? (TSEQ - 1 - t) : t;
    const float* base = x + ((size_t)arow0 * TSEQ + tx) * DIN;
    #pragma unroll
    for (int kc = 0; kc < 2; ++kc) {
      const float* p = base + wx + kc * 32 + quad * 8;
      xr[kc][0] = *reinterpret_cast<const float8_*>(p);
      xr[kc][1] = *reinterpret_cast<const float8_*>(p + (size_t)16 * TSEQ * DIN);
    }
  };
  auto gemm_x_regs = [&]() {
    #pragma unroll
    for (int kc = 0; kc < 2; ++kc) {
      short8 a0 = cvt8v(xr[kc][0]);
      short8 a1 = cvt8v(xr[kc][1]);
      #pragma unroll
      for (int nt = 0; nt < 4; ++nt) {
        acc[0][nt] = __builtin_amdgcn_mfma_f32_16x16x32_bf16(a0, Bf[kc][nt], acc[0][nt], 0, 0, 0);
        acc[1][nt] = __builtin_amdgcn_mfma_f32_16x16x32_bf16(a1, Bf[kc][nt], acc[1][nt], 0, 0, 0);
      }
    }
  };

  // recurrent part with DATA-POLL: load own fragments of parity (t-1)&3
  // until sentinel-free, then MFMA straight out of the polled registers.
  auto gemm_h = [&](int t) {
    const int rp = (t + 3) & 3;               // parity holding h(t-1)
    const unsigned long long* base[4];
    #pragma unroll
    for (int kc = 0; kc < 4; ++kc) {
      const int kh = wh + kc * 32 + quad * 8;
      base[kc] = hbuf64 + ((((size_t)(rp * 64 + arow0)) * 1024 + kh) >> 2);
    }
    unsigned long long v[4][4];
    int it = 0;
    for (;;) {
      #pragma unroll
      for (int kc = 0; kc < 4; ++kc) {
        v[kc][0] = __hip_atomic_load(base[kc],        __ATOMIC_RELAXED, __HIP_MEMORY_SCOPE_AGENT);
        v[kc][1] = __hip_atomic_load(base[kc] + 1,    __ATOMIC_RELAXED, __HIP_MEMORY_SCOPE_AGENT);
        v[kc][2] = __hip_atomic_load(base[kc] + 4096, __ATOMIC_RELAXED, __HIP_MEMORY_SCOPE_AGENT);
        v[kc][3] = __hip_atomic_load(base[kc] + 4097, __ATOMIC_RELAXED, __HIP_MEMORY_SCOPE_AGENT);
      }
      // sentinel scan: any 16-bit lane == 0xFFFF  <=>  ~v has a zero lane
      unsigned long long bad = 0;
      #pragma unroll
      for (int kc = 0; kc < 4; ++kc)
        #pragma unroll
        for (int j = 0; j < 4; ++j) {
          unsigned long long y = ~v[kc][j];
          bad |= (y - 0x0001000100010001ull) & ~y & 0x8000800080008000ull;
        }
      if (__ballot(bad != 0) == 0ull) break;
      if (++it > 200000) break;               // bounded: never hard-hang
      if (it < 4) __builtin_amdgcn_s_sleep(1);
      else        __builtin_amdgcn_s_sleep(4);
    }
    #pragma unroll
    for (int kc = 0; kc < 4; ++kc) {
      union { unsigned long long u[2]; short8 s; } a0, a1;
      a0.u[0] = v[kc][0]; a0.u[1] = v[kc][1];
      a1.u[0] = v[kc][2]; a1.u[1] = v[kc][3];
      #pragma unroll
      for (int nt = 0; nt < 4; ++nt) {
        acc[0][nt] = __builtin_amdgcn_mfma_f32_16x16x32_bf16(a0.s, Bf[kc + 2][nt], acc[0][nt], 0, 0, 0);
        acc[1][nt] = __builtin_amdgcn_mfma_f32_16x16x32_bf16(a1.s, Bf[kc + 2][nt], acc[1][nt], 0, 0, 0);
      }
    }
  };

  xload(0);
  gemm_x_regs();                              // x-part of step 0 (all waves)

  const int row_l = wv * 4 + quad;
  const int bglob = group * 32 + row_l;

  for (int t = 0; t < TSEQ; ++t) {
    // pre-poison parity (t+1)&3 of MY seg region with sentinel.
    // Safe: its readers would be at step t-2 (all peers are >= t-1), its
    // only writer at t+1 writes a disjoint region. Drained to L3 by the
    // mid-step __syncthreads BELOW, i.e. before h(t) publishes.
    {
      const int rq = (t + 1) & 3;
      if (tid < 256) {
        const int rr = group * 32 + (tid >> 3);
        const int uu = j0 + ((tid & 7) << 1);
        const size_t elem = (size_t)(rq * 64 + rr) * 1024 + uu;
        __hip_atomic_store(hbuf32 + (elem >> 1), 0xFFFFFFFFu,
                           __ATOMIC_RELAXED, __HIP_MEMORY_SCOPE_AGENT);
      }
    }

    gemm_h(t);                                // per-wave data-poll + MFMA

    #pragma unroll
    for (int mt = 0; mt < 2; ++mt)
      #pragma unroll
      for (int nt = 0; nt < 4; ++nt)
        #pragma unroll
        for (int r = 0; r < 4; ++r)
          part[wv][nt][mt * 16 + quad * 4 + r][u16] = acc[mt][nt][r];
    __syncthreads();   // FULL sync: drains poison stores to L3 (vmcnt 0)

    // issue x(t+1) loads NOW — they retire during reduce/act/publish/poll,
    // so the tail's cvt+MFMA never stalls on HBM latency.
    if (t + 1 < TSEQ) xload(t + 1);

    float gts[4];
    #pragma unroll
    for (int g = 0; g < 4; ++g) {
      float s = bias[g];
      #pragma unroll
      for (int p = 0; p < 8; ++p) s += part[p][g][row_l][u16];
      gts[g] = s;
    }
    float iv = fsig(gts[0]);
    float fv = fsig(gts[1]);
    float gv = ftanh(gts[2]);
    float ov = fsig(gts[3]);
    cstate = fv * cstate + iv * gv;
    float hv = ov * ftanh(cstate);
    unsigned short h16 = f2bf(hv);

    // publish h(t) at parity t&3: packed bf16 pairs, relaxed agent stores.
    // No ack wait — consumers detect the data itself.
    {
      unsigned int h32 = h16;
      unsigned int oth = __shfl_xor(h32, 1);
      if ((u16 & 1) == 0) {
        unsigned int val = h32 | (oth << 16);
        size_t elem = (size_t)((t & 3) * 64 + bglob) * 1024 + j0 + u16;
        __hip_atomic_store(hbuf32 + (elem >> 1), val,
                           __ATOMIC_RELAXED, __HIP_MEMORY_SCOPE_AGENT);
      }
    }

    // end barrier: LDS-only (protects part[] reuse). h/out/x-load traffic
    // stays in flight; drains at the NEXT mid-step __syncthreads.
    asm volatile("s_waitcnt lgkmcnt(0)" ::: "memory");
    __builtin_amdgcn_s_barrier();
    __builtin_amdgcn_sched_barrier(0);

    // hidden_states[b][t][dir*1024+j] in FULL f32 — off the critical path
    out[((size_t)bglob * TSEQ + t) * 2048 + dir * 1024 + j0 + u16] = hv;

    #pragma unroll
    for (int mt = 0; mt < 2; ++mt)
      #pragma unroll
      for (int nt = 0; nt < 4; ++nt) acc[mt][nt] = (float4_){0.f, 0.f, 0.f, 0.f};
    if (t + 1 < TSEQ) gemm_x_regs();          // cvt+MFMA from long-retired regs
  }

  // publish final cell state (bf16, coherence-point)
  {
    unsigned short c16 = f2bf(cstate);
    unsigned int c32 = c16;
    unsigned int oth = __shfl_xor(c32, 1);
    if ((u16 & 1) == 0) {
      size_t elem = (size_t)bglob * 2048 + dir * 1024 + j0 + u16;
      __hip_atomic_store((unsigned int*)cend + (elem >> 1), c32 | (oth << 16),
                         __ATOMIC_RELAXED, __HIP_MEMORY_SCOPE_AGENT);
    }
  }
  __syncthreads();                            // FULL: drain cend + out stores
  if (tid == 0)
    __hip_atomic_store(done + wg, 1, __ATOMIC_RELAXED, __HIP_MEMORY_SCOPE_AGENT);
  if (wg >= 128) return;                      // only epilogue WGs wait

  {
    int it = 0;
    for (;;) {
      int ok = 1;
      #pragma unroll
      for (int j = 0; j < 4; ++j) {
        int v = __hip_atomic_load(done + lane * 4 + j, __ATOMIC_RELAXED, __HIP_MEMORY_SCOPE_AGENT);
        ok &= (v != 0);
      }
      if (__ballot(!ok) == 0ull) break;
      if (++it > 300000) break;
      __builtin_amdgcn_s_sleep(4);
    }
    __builtin_amdgcn_fence(__ATOMIC_ACQUIRE, "workgroup");
    __builtin_amdgcn_sched_barrier(0);
  }
  if (wv >= 4) return;

  // epilogue: initial_hiddens = tanh(h_end @ fh_W^T + fh_b)   (mat 0)
  //           initial_cells   = tanh(c_end @ fc_W^T + fc_b)   (mat 1)
  const int mat   = wg >> 6;
  const int nbase = (wg & 63) * 16;
  const float* Wp = mat ? fcW : fhW;
  const float* bp = mat ? fcb : fhb;
  const int m0 = wv * 16;
  const int am = m0 + u16;
  const unsigned long long* hf64 = (const unsigned long long*)hbuf_f;
  const unsigned long long* hb64 = (const unsigned long long*)hbuf_b;
  const unsigned long long* ce64 = (const unsigned long long*)cend;
  float4_ a4 = (float4_){0.f, 0.f, 0.f, 0.f};
  #pragma unroll 4
  for (int kc = 0; kc < 64; ++kc) {
    const int k = kc * 32 + quad * 8;
    short8 av, bv;
    if (mat == 0) {                          // h(511) lives at parity 3
      av = (kc < 32) ? ald16(hf64, (size_t)(192 + am) * 1024 + k)
                     : ald16(hb64, (size_t)(192 + am) * 1024 + (k - 1024));
    } else {
      av = ald16(ce64, (size_t)am * 2048 + k);
    }
    bv = cvt8(Wp + (size_t)(nbase + u16) * 2048 + k);
    a4 = __builtin_amdgcn_mfma_f32_16x16x32_bf16(av, bv, a4, 0, 0, 0);
  }
  float bb = bp[nbase + u16];
  #pragma unroll
  for (int r = 0; r < 4; ++r) {
    const int row = m0 + quad * 4 + r;
    float v = ftanh(a4[r] + bb);
    out[(size_t)67108864 + (size_t)mat * 65536 + (size_t)row * 1024 + nbase + u16] = v;
  }
}

extern "C" void kernel_launch(void* const* d_in, const int* in_sizes, int n_in,
                              void* d_out, int out_size, void* d_ws, size_t ws_size,
                              hipStream_t stream) {
  char* ws = (char*)d_ws;
  // ws map: [0,1KB) done (256 ints, 4KB reserved),
  //         [4KB, +512KB) h_f 4-parity ring, +512KB h_b ring, +256KB c_end
  int* done = (int*)(ws);
  unsigned short* hf = (unsigned short*)(ws + 4096);
  unsigned short* hb = (unsigned short*)(ws + 4096 + 524288);
  unsigned short* ce = (unsigned short*)(ws + 4096 + 1048576);
  (void)hipMemsetAsync(ws, 0, 4096, stream);                   // done = 0
  (void)hipMemsetAsync(hf, 0xFF, 393216, stream);              // parities 0-2 poison
  (void)hipMemsetAsync((char*)hf + 393216, 0, 131072, stream); // parity 3 = h(-1) = 0
  (void)hipMemsetAsync(hb, 0xFF, 393216, stream);
  (void)hipMemsetAsync((char*)hb + 393216, 0, 131072, stream);
  lstm_encoder_kernel<<<256, 512, 0, stream>>>(
      (const float*)d_in[0],
      (const float*)d_in[1], (const float*)d_in[2],
      (const float*)d_in[3], (const float*)d_in[4],
      (const float*)d_in[5], (const float*)d_in[6],
      (const float*)d_in[7], (const float*)d_in[8],
      (const float*)d_in[9], (const float*)d_in[10],
      (const float*)d_in[11], (const float*)d_in[12],
      (float*)d_out, done, hf, hb, ce);
}